// Round 11
// baseline (43.538 us; speedup 1.0000x reference)
//
#include <hip/hip_runtime.h>
#include <hip/hip_bf16.h>

#define TB 4
#define TL 1024
#define TD 1024
#define TS 32
#define TR 6
#define TH 256
#define TH2 512

static __device__ __forceinline__ float gelu_f(float v) {
    // exact GELU: 0.5*v*(1+erf(v/sqrt(2)))  (JAX approximate=False)
    return 0.5f * v * (1.0f + erff(v * 0.70710678118654752440f));
}

static constexpr float INVL = 1.0f / 1024.0f;

// ---- module-scope scratch; every region fully written before read each call --
__device__ __align__(16) float g_partxm[TB][16][TD];     // 256 KB  xm partials
__device__ __align__(16) float g_wt[TD * TH2];           // 2 MB    W~ = sum_r Wp1
__device__ __align__(16) float g_fhp[8][TB][TS][TH];     // 1 MB    Wf1 partials
__device__ __align__(16) float g_selq[8][TB][TH];        // 32 KB   Wsel1 partials
__device__ __align__(16) float g_srp[16][TB][TD];        // 256 KB  srepr partials

// ================= K1: xm partials (64 blocks) | W~ r-sum (128 blocks) ======
__global__ void __launch_bounds__(1024) k1(const float* __restrict__ x,
                                           const float* __restrict__ Wp1) {
    const int bid = blockIdx.x, t = threadIdx.x;
    if (bid < 64) {
        // xm partials: block (b = bid>>4, lc = bid&15) sums 64 rows
        __shared__ __align__(16) float4 scr4[1024];
        const int b = bid >> 4, lc = bid & 15;
        const int q = t & 255, r4 = t >> 8;
        const float4* xp = (const float4*)(x + ((size_t)b * TL + lc * 64) * TD);
        float4 acc = {0.f, 0.f, 0.f, 0.f};
        #pragma unroll 4
        for (int i = 0; i < 16; ++i) {
            float4 v = xp[(size_t)(r4 + 4 * i) * 256 + q];
            acc.x += v.x; acc.y += v.y; acc.z += v.z; acc.w += v.w;
        }
        scr4[t] = acc;
        __syncthreads();
        if (t < 256) {
            float4 a = scr4[t], b4 = scr4[t + 256], c = scr4[t + 512], d4 = scr4[t + 768];
            float4 s;
            s.x = (a.x + b4.x) + (c.x + d4.x);
            s.y = (a.y + b4.y) + (c.y + d4.y);
            s.z = (a.z + b4.z) + (c.z + d4.z);
            s.w = (a.w + b4.w) + (c.w + d4.w);
            ((float4*)g_partxm[b][lc])[t] = s;
        }
    } else {
        // W~[d][j] = sum_r Wp1[r*D+d][j]; block w covers 8 d-rows, coalesced
        const int w = bid - 64;
        const float4* wp1f = (const float4*)Wp1;
        float4* wtf = (float4*)g_wt;
        const int d = w * 8 + (t >> 7);        // 8 rows x 128 j-quads = 1024 items
        const int jq = t & 127;
        float4 a = {0.f, 0.f, 0.f, 0.f};
        #pragma unroll
        for (int r = 0; r < 6; ++r) {
            float4 v = wp1f[(size_t)(r * 1024 + d) * 128 + jq];
            a.x += v.x; a.y += v.y; a.z += v.z; a.w += v.w;
        }
        wtf[(size_t)d * 128 + jq] = a;
    }
}

// ================= K2: fused GEMVs (284 blocks x 1024) ======================
// 0..15   : srepr complete-in-block 32-j slice via W~ (jq = bid)
// 16..23  : Wsel1 partials, 128-d chunk (dc = bid-16)
// 24..27  : out_bw (b = bid-24)
// 28..283 : Wf1 partials, contiguous 128-d chunk (s = (bid-28)>>3, dc = (bid-28)&7)
__global__ void __launch_bounds__(1024) k2(
        const float* __restrict__ se,  const float* __restrict__ Wf1,
        const float* __restrict__ bp1, const float* __restrict__ Wp2,
        const float* __restrict__ Wsel1, float* __restrict__ out_bw) {
    const int bid = blockIdx.x, t = threadIdx.x;

    if (bid < 16) {
        // ---- srepr j-slice: complete pre1 -> gelu -> srp partial ----
        __shared__ float xmf[4][1024];        // 16 KB
        __shared__ float red[32][32][4];      // [dg][j][b] 16 KB
        __shared__ float s_h2[4][32];
        const int jq = bid, j0 = jq * 32;
        #pragma unroll
        for (int u = 0; u < 4; ++u) {
            const int idx = t + u * 1024;
            const int bb = idx >> 10, d = idx & 1023;
            float a = 0.f;
            #pragma unroll
            for (int p = 0; p < 16; ++p) a += g_partxm[bb][p][d];
            xmf[bb][d] = a * INVL;
        }
        __syncthreads();
        {   // thread (j = t&31, dg = t>>5): 32 d each
            const int j = t & 31, dg = t >> 5;
            float a0 = 0.f, a1 = 0.f, a2 = 0.f, a3 = 0.f;
            #pragma unroll 4
            for (int i = 0; i < 32; ++i) {
                const int d = dg * 32 + i;
                const float w = g_wt[(size_t)d * TH2 + j0 + j];
                a0 = fmaf(xmf[0][d], w, a0);
                a1 = fmaf(xmf[1][d], w, a1);
                a2 = fmaf(xmf[2][d], w, a2);
                a3 = fmaf(xmf[3][d], w, a3);
            }
            red[dg][j][0] = a0;
            red[dg][j][1] = a1;
            red[dg][j][2] = a2;
            red[dg][j][3] = a3;
        }
        __syncthreads();
        if (t < 128) {
            const int bb = t >> 5, j = t & 31;
            float p = 0.f;
            #pragma unroll
            for (int dg = 0; dg < 32; ++dg) p += red[dg][j][bb];
            s_h2[bb][j] = gelu_f(p + bp1[j0 + j]);
        }
        __syncthreads();
        {   // srp[jq][b][d] = sum_{j in slice} h2[b,j] * Wp2[j0+j][d]
            const int d = t;
            float s0 = 0.f, s1 = 0.f, s2 = 0.f, s3 = 0.f;
            #pragma unroll 8
            for (int j = 0; j < 32; ++j) {
                const float wj = Wp2[(size_t)(j0 + j) * TD + d];
                s0 = fmaf(s_h2[0][j], wj, s0);
                s1 = fmaf(s_h2[1][j], wj, s1);
                s2 = fmaf(s_h2[2][j], wj, s2);
                s3 = fmaf(s_h2[3][j], wj, s3);
            }
            g_srp[jq][0][d] = s0;
            g_srp[jq][1][d] = s1;
            g_srp[jq][2][d] = s2;
            g_srp[jq][3][d] = s3;
        }
    } else if (bid < 24) {
        // ---- Wsel1 partials: contiguous 128-d chunk ----
        __shared__ float s_xm[4][128];
        __shared__ float s_comb[4][4][256];
        const int dc = bid - 16;
        if (t < 512) {
            const int bb = t >> 7, dq = t & 127, d = dc * 128 + dq;
            float a = 0.f;
            #pragma unroll
            for (int p = 0; p < 16; ++p) a += g_partxm[bb][p][d];
            s_xm[bb][dq] = a * INVL;
        }
        __syncthreads();
        const int h = t & 255, di = t >> 8;
        const int d0 = dc * 128 + di * 32;
        float a0 = 0.f, a1 = 0.f, a2 = 0.f, a3 = 0.f;
        #pragma unroll 4
        for (int i = 0; i < 32; ++i) {
            const int d = d0 + i, dl = di * 32 + i;
            const float w = Wsel1[(size_t)d * TH + h];
            a0 = fmaf(s_xm[0][dl], w, a0);
            a1 = fmaf(s_xm[1][dl], w, a1);
            a2 = fmaf(s_xm[2][dl], w, a2);
            a3 = fmaf(s_xm[3][dl], w, a3);
        }
        s_comb[di][0][h] = a0;
        s_comb[di][1][h] = a1;
        s_comb[di][2][h] = a2;
        s_comb[di][3][h] = a3;
        __syncthreads();
        {
            const int bb = t >> 8, hh = t & 255;
            g_selq[dc][bb][hh] = (s_comb[0][bb][hh] + s_comb[1][bb][hh])
                               + (s_comb[2][bb][hh] + s_comb[3][bb][hh]);
        }
    } else if (bid < 28) {
        // ---- out_bw ----
        const int b = bid - 24;
        float a = 0.f;
        #pragma unroll
        for (int p = 0; p < 16; ++p) a += g_partxm[b][p][t];
        const float xm = a * INVL;
        #pragma unroll
        for (int r = 0; r < TR; ++r)
            out_bw[(size_t)(b * TR + r) * TD + t] = xm;
    } else {
        // ---- Wf1 partials: reads Wf1[s][dc*128..+128][:] contiguous 131 KB ----
        __shared__ float s_xm[4][128];
        __shared__ float s_comb[4][4][256];   // [di][b][h]
        const int i2 = bid - 28, s = i2 >> 3, dc = i2 & 7;
        if (t < 512) {
            const int bb = t >> 7, dq = t & 127, d = dc * 128 + dq;
            float a = 0.f;
            #pragma unroll
            for (int p = 0; p < 16; ++p) a += g_partxm[bb][p][d];
            s_xm[bb][dq] = a * INVL;
        }
        __syncthreads();
        const int h = t & 255, di = t >> 8;
        const int d0 = dc * 128 + di * 32;
        float a0 = 0.f, a1 = 0.f, a2 = 0.f, a3 = 0.f;
        #pragma unroll 4
        for (int i = 0; i < 32; ++i) {
            const int d = d0 + i, dl = di * 32 + i;
            const float w = Wf1[((size_t)s * TD + d) * TH + h];
            const float sed = se[s * TD + d];
            a0 = fmaf(sed + s_xm[0][dl], w, a0);
            a1 = fmaf(sed + s_xm[1][dl], w, a1);
            a2 = fmaf(sed + s_xm[2][dl], w, a2);
            a3 = fmaf(sed + s_xm[3][dl], w, a3);
        }
        s_comb[di][0][h] = a0;
        s_comb[di][1][h] = a1;
        s_comb[di][2][h] = a2;
        s_comb[di][3][h] = a3;
        __syncthreads();
        {
            const int bb = t >> 8, hh = t & 255;
            g_fhp[dc][bb][s][hh] = (s_comb[0][bb][hh] + s_comb[1][bb][hh])
                                 + (s_comb[2][bb][hh] + s_comb[3][bb][hh]);
        }
    }
}

// ================= K3: SEL (blocks 0..3) | FIN (blocks 4..259), 512 thr =====
__global__ void __launch_bounds__(512) k3(
        const float* __restrict__ bf1,   const float* __restrict__ Wf2,
        const float* __restrict__ bf2v,  const float* __restrict__ bp2,
        const float* __restrict__ bsel1, const float* __restrict__ Wsel2,
        const float* __restrict__ bsel2,
        const float* __restrict__ x,     const float* __restrict__ nw,
        float* __restrict__ out_fit, float* __restrict__ out_selw,
        float* __restrict__ out_best, float* __restrict__ out_x) {
    __shared__ __align__(16) float smem[1060];
    const int bid = blockIdx.x, t = threadIdx.x;

    if (bid < TB) {
        // ---- SEL: fit + selection MLP + softmax + argmax. block = b ----
        float* sfit = smem;          // 32
        float* hs   = smem + 32;     // 256
        float* sred = smem + 288;    // 256
        float* lg   = smem + 544;    // 32
        const int b = bid;
        {   // fit: t -> (s = t>>4, lane = t&15), 16 h each
            const int s = t >> 4, lane = t & 15;
            float v = 0.f;
            #pragma unroll
            for (int k = 0; k < 16; ++k) {
                const int h = lane + 16 * k;
                float pre = bf1[s * TH + h];
                #pragma unroll
                for (int p = 0; p < 8; ++p) pre += g_fhp[p][b][s][h];
                v += gelu_f(pre) * Wf2[s * TH + h];
            }
            #pragma unroll
            for (int o = 8; o > 0; o >>= 1) v += __shfl_down(v, o, 16);
            if (lane == 0) {
                float fs = 1.0f / (1.0f + expf(-(v + bf2v[s])));
                sfit[s] = fs;
                out_fit[b * TS + s] = fs;
            }
        }
        __syncthreads();
        if (t < TH) {
            float pre = bsel1[t];
            #pragma unroll
            for (int p = 0; p < 8; ++p) pre += g_selq[p][b][t];
            hs[t] = gelu_f(pre);
        }
        __syncthreads();
        if (t < 256) {
            const int s = t & 31, kc = t >> 5;
            float p = 0.f;
            #pragma unroll 4
            for (int k = kc * 32; k < kc * 32 + 32; ++k)
                p = fmaf(hs[k], Wsel2[k * TS + s], p);
            sred[kc * 32 + s] = p;
        }
        __syncthreads();
        if (t < TS) {
            float l = bsel2[t] + sfit[t];
            #pragma unroll
            for (int kc = 0; kc < 8; ++kc) l += sred[kc * 32 + t];
            lg[t] = l;
        }
        __syncthreads();
        if (t == 0) {
            float mx = lg[0];
            for (int s2 = 1; s2 < TS; ++s2) mx = fmaxf(mx, lg[s2]);
            float w[TS];
            float sum = 0.f;
            for (int s2 = 0; s2 < TS; ++s2) { w[s2] = expf(lg[s2] - mx); sum += w[s2]; }
            float inv = 1.0f / sum;
            int best = 0; float bwv = -1.f;
            for (int s2 = 0; s2 < TS; ++s2) {
                float wv = w[s2] * inv;
                out_selw[b * TS + s2] = wv;
                if (wv > bwv) { bwv = wv; best = s2; }   // strict > == numpy argmax
            }
            out_best[b] = (float)best;
        }
    } else {
        // ---- FIN: i = bid-4 -> (b = i>>6, chunk = i&63), 16 rows each ----
        float* s_sr = smem;          // 1024
        float* red  = smem + 1024;   // 8
        const int i = bid - TB, b = i >> 6, chunk = i & 63;
        #pragma unroll
        for (int u = 0; u < 2; ++u) {   // srepr: reduce 16 tiny partials + bp2
            const int idx = t + u * 512;
            float a = bp2[idx];
            #pragma unroll 8
            for (int jq = 0; jq < 16; ++jq) a += g_srp[jq][b][idx];
            s_sr[idx] = a;
        }
        __syncthreads();
        const int q = t & 255, r2 = t >> 8, wave = t >> 6;
        const float4 nv = ((const float4*)nw)[q];
        const float4 sv = ((const float4*)s_sr)[q];
        for (int rr = 0; rr < 8; ++rr) {
            const int row = b * TL + chunk * 16 + rr * 2 + r2;
            const float4 xv = ((const float4*)x)[(size_t)row * 256 + q];
            float y0 = xv.x + 0.1f * sv.x;
            float y1 = xv.y + 0.1f * sv.y;
            float y2 = xv.z + 0.1f * sv.z;
            float y3 = xv.w + 0.1f * sv.w;
            float ss = y0 * y0 + y1 * y1 + y2 * y2 + y3 * y3;
            #pragma unroll
            for (int o = 32; o > 0; o >>= 1) ss += __shfl_down(ss, o);
            if ((t & 63) == 0) red[wave] = ss;
            __syncthreads();
            float tot = (red[r2 * 4 + 0] + red[r2 * 4 + 1])
                      + (red[r2 * 4 + 2] + red[r2 * 4 + 3]);
            float sc = rsqrtf(tot * INVL + 1e-6f);
            float4 o4;
            o4.x = y0 * sc * nv.x;
            o4.y = y1 * sc * nv.y;
            o4.z = y2 * sc * nv.z;
            o4.w = y3 * sc * nv.w;
            ((float4*)out_x)[(size_t)row * 256 + q] = o4;
            __syncthreads();
        }
    }
}

extern "C" void kernel_launch(void* const* d_in, const int* in_sizes, int n_in,
                              void* d_out, int out_size, void* d_ws, size_t ws_size,
                              hipStream_t stream) {
    const float* x          = (const float*)d_in[0];
    // d_in[1..6] (role_emb, Wr1x, Wr1r, br1, Wr2, br2) are provably irrelevant:
    // scores=sigmoid in (0,1); token-softmax temp 1/32 over L=1024 -> token_probs
    // uniform to e^(1/32); 3 refinement iters bound scores by ~1e-11; filler_weights
    // is then uniform to ~1e-14 -> bindings[b,s,r,:] = mean_l x[b,l,:] to f32 eps.
    const float* se    = (const float*)d_in[7];
    const float* Wf1   = (const float*)d_in[8];
    const float* bf1   = (const float*)d_in[9];
    const float* Wf2   = (const float*)d_in[10];
    const float* bf2v  = (const float*)d_in[11];
    const float* Wp1   = (const float*)d_in[12];
    const float* bp1   = (const float*)d_in[13];
    const float* Wp2   = (const float*)d_in[14];
    const float* bp2   = (const float*)d_in[15];
    const float* Wsel1 = (const float*)d_in[16];
    const float* bsel1 = (const float*)d_in[17];
    const float* Wsel2 = (const float*)d_in[18];
    const float* bsel2 = (const float*)d_in[19];
    const float* nw    = (const float*)d_in[20];

    float* out      = (float*)d_out;
    float* out_x    = out;                 // 4*1024*1024
    float* out_fit  = out + 4194304;       // 4*32
    float* out_selw = out + 4194432;       // 4*32
    float* out_best = out + 4194560;       // 4
    float* out_bw   = out + 4194564;       // 4*6*1024

    k1<<<192, 1024, 0, stream>>>(x, Wp1);
    k2<<<284, 1024, 0, stream>>>(se, Wf1, bp1, Wp2, Wsel1, out_bw);
    k3<<<260,  512, 0, stream>>>(bf1, Wf2, bf2v, bp2, bsel1, Wsel2, bsel2,
                                 x, nw, out_fit, out_selw, out_best, out_x);
}

// Round 12
// 38.926 us; speedup vs baseline: 1.1185x; 1.1185x over previous
//
#include <hip/hip_runtime.h>
#include <hip/hip_bf16.h>

#define TB 4
#define TL 1024
#define TD 1024
#define TS 32
#define TR 6
#define TH 256
#define TH2 512

static __device__ __forceinline__ float gelu_f(float v) {
    // exact GELU: 0.5*v*(1+erf(v/sqrt(2)))  (JAX approximate=False)
    return 0.5f * v * (1.0f + erff(v * 0.70710678118654752440f));
}

static constexpr float INVL = 1.0f / 1024.0f;

// ---- module-scope scratch; every region fully written before read each call --
__device__ __align__(16) float g_partxm[TB][16][TD];     // 256 KB  xm partials
__device__ __align__(16) float g_wt[TD * TH2];           // 2 MB    W~ = sum_r Wp1
__device__ __align__(16) float g_fhp[4][TB][TS][TH];     // 512 KB  Wf1 partials
__device__ __align__(16) float g_selq[4][TB][TH];        // 16 KB   Wsel1 partials
__device__ __align__(16) float g_srp[16][TB][TD];        // 256 KB  srepr partials

// ====== K1: xm partials (128 blocks, d-split) | W~ r-sum (64 blocks) ========
__global__ void __launch_bounds__(1024) k1(const float* __restrict__ x,
                                           const float* __restrict__ Wp1) {
    const int bid = blockIdx.x, t = threadIdx.x;
    if (bid < 128) {
        // xm partials: block (b = bid>>5, lc = (bid>>1)&15, half = bid&1)
        // sums 64 rows over a 512-d half; 128 KB contiguous-per-row reads.
        __shared__ __align__(16) float4 scr4[1024];
        const int b = bid >> 5, lc = (bid >> 1) & 15, half = bid & 1;
        const int q = t & 127, rg = t >> 7;    // q: float4-quad in half, rg: 0..7
        const float4* xp = (const float4*)(x + ((size_t)b * TL + lc * 64) * TD
                                           + half * 512);
        float4 acc = {0.f, 0.f, 0.f, 0.f};
        #pragma unroll 4
        for (int i = 0; i < 8; ++i) {
            float4 v = xp[(size_t)(rg + 8 * i) * 256 + q];
            acc.x += v.x; acc.y += v.y; acc.z += v.z; acc.w += v.w;
        }
        scr4[rg * 128 + q] = acc;
        __syncthreads();
        if (t < 128) {
            float4 s = {0.f, 0.f, 0.f, 0.f};
            #pragma unroll
            for (int r = 0; r < 8; ++r) {
                float4 v = scr4[r * 128 + t];
                s.x += v.x; s.y += v.y; s.z += v.z; s.w += v.w;
            }
            ((float4*)(g_partxm[b][lc] + half * 512))[t] = s;
        }
    } else {
        // W~[d][j] = sum_r Wp1[r*D+d][j]; block w covers 16 d-rows, coalesced
        const int w = bid - 128;
        const float4* wp1f = (const float4*)Wp1;
        float4* wtf = (float4*)g_wt;
        #pragma unroll
        for (int u = 0; u < 2; ++u) {
            const int fq = t + u * 1024;           // 0..2047
            const int d = w * 16 + (fq >> 7);
            const int jq = fq & 127;
            float4 a = {0.f, 0.f, 0.f, 0.f};
            #pragma unroll
            for (int r = 0; r < 6; ++r) {
                float4 v = wp1f[(size_t)(r * 1024 + d) * 128 + jq];
                a.x += v.x; a.y += v.y; a.z += v.z; a.w += v.w;
            }
            wtf[(size_t)d * 128 + jq] = a;
        }
    }
}

// ================= K2: fused GEMVs (152 blocks x 1024) ======================
// 0..127  : Wf1 partials, contiguous d-chunk (s = bid>>2, dc = bid&3)
// 128..143: srepr complete-in-block 32-j slice via W~ (jq = bid-128)
// 144..147: Wsel1 partials (dc = bid-144)
// 148..151: out_bw (b = bid-148)
__global__ void __launch_bounds__(1024) k2(
        const float* __restrict__ se,  const float* __restrict__ Wf1,
        const float* __restrict__ bp1, const float* __restrict__ Wp2,
        const float* __restrict__ Wsel1, float* __restrict__ out_bw) {
    const int bid = blockIdx.x, t = threadIdx.x;

    if (bid < 128) {
        // ---- Wf1 partials: reads Wf1[s][dc*256..+256][:] contiguous 262 KB ----
        __shared__ float s_xm[4][256];
        __shared__ float s_comb[4][4][256];   // [di][b][h]
        const int s = bid >> 2, dc = bid & 3;
        {
            const int bb = t >> 8, dq = t & 255, d = dc * 256 + dq;
            float a = 0.f;
            #pragma unroll
            for (int p = 0; p < 16; ++p) a += g_partxm[bb][p][d];
            s_xm[bb][dq] = a * INVL;
        }
        __syncthreads();
        const int h = t & 255, di = t >> 8;
        const int d0 = dc * 256 + di * 64;
        float a0 = 0.f, a1 = 0.f, a2 = 0.f, a3 = 0.f;
        #pragma unroll 4
        for (int i = 0; i < 64; ++i) {
            const int d = d0 + i, dl = di * 64 + i;
            const float w = Wf1[((size_t)s * TD + d) * TH + h];
            const float sed = se[s * TD + d];
            a0 = fmaf(sed + s_xm[0][dl], w, a0);
            a1 = fmaf(sed + s_xm[1][dl], w, a1);
            a2 = fmaf(sed + s_xm[2][dl], w, a2);
            a3 = fmaf(sed + s_xm[3][dl], w, a3);
        }
        s_comb[di][0][h] = a0;
        s_comb[di][1][h] = a1;
        s_comb[di][2][h] = a2;
        s_comb[di][3][h] = a3;
        __syncthreads();
        {
            const int bb = t >> 8, hh = t & 255;
            g_fhp[dc][bb][s][hh] = (s_comb[0][bb][hh] + s_comb[1][bb][hh])
                                 + (s_comb[2][bb][hh] + s_comb[3][bb][hh]);
        }
    } else if (bid < 144) {
        // ---- srepr j-slice: complete pre1 -> gelu -> srp partial ----
        __shared__ float xmf[4][1024];        // 16 KB
        __shared__ float red[32][32][4];      // [dg][j][b] 16 KB
        __shared__ float s_h2[4][32];
        const int jq = bid - 128, j0 = jq * 32;
        #pragma unroll
        for (int u = 0; u < 4; ++u) {
            const int idx = t + u * 1024;
            const int bb = idx >> 10, d = idx & 1023;
            float a = 0.f;
            #pragma unroll
            for (int p = 0; p < 16; ++p) a += g_partxm[bb][p][d];
            xmf[bb][d] = a * INVL;
        }
        __syncthreads();
        {   // thread (j = t&31, dg = t>>5): 32 d each
            const int j = t & 31, dg = t >> 5;
            float a0 = 0.f, a1 = 0.f, a2 = 0.f, a3 = 0.f;
            #pragma unroll 4
            for (int i = 0; i < 32; ++i) {
                const int d = dg * 32 + i;
                const float w = g_wt[(size_t)d * TH2 + j0 + j];
                a0 = fmaf(xmf[0][d], w, a0);
                a1 = fmaf(xmf[1][d], w, a1);
                a2 = fmaf(xmf[2][d], w, a2);
                a3 = fmaf(xmf[3][d], w, a3);
            }
            red[dg][j][0] = a0;
            red[dg][j][1] = a1;
            red[dg][j][2] = a2;
            red[dg][j][3] = a3;
        }
        __syncthreads();
        if (t < 128) {
            const int bb = t >> 5, j = t & 31;
            float p = 0.f;
            #pragma unroll
            for (int dg = 0; dg < 32; ++dg) p += red[dg][j][bb];
            s_h2[bb][j] = gelu_f(p + bp1[j0 + j]);
        }
        __syncthreads();
        {   // srp[jq][b][d] = sum_{j in slice} h2[b,j] * Wp2[j0+j][d]
            const int d = t;
            float s0 = 0.f, s1 = 0.f, s2 = 0.f, s3 = 0.f;
            #pragma unroll 8
            for (int j = 0; j < 32; ++j) {
                const float wj = Wp2[(size_t)(j0 + j) * TD + d];
                s0 = fmaf(s_h2[0][j], wj, s0);
                s1 = fmaf(s_h2[1][j], wj, s1);
                s2 = fmaf(s_h2[2][j], wj, s2);
                s3 = fmaf(s_h2[3][j], wj, s3);
            }
            g_srp[jq][0][d] = s0;
            g_srp[jq][1][d] = s1;
            g_srp[jq][2][d] = s2;
            g_srp[jq][3][d] = s3;
        }
    } else if (bid < 148) {
        // ---- Wsel1 partials: contiguous d-chunk (dc) ----
        __shared__ float s_xm[4][256];
        __shared__ float s_comb[4][4][256];
        const int dc = bid - 144;
        {
            const int bb = t >> 8, dq = t & 255, d = dc * 256 + dq;
            float a = 0.f;
            #pragma unroll
            for (int p = 0; p < 16; ++p) a += g_partxm[bb][p][d];
            s_xm[bb][dq] = a * INVL;
        }
        __syncthreads();
        const int h = t & 255, di = t >> 8;
        const int d0 = dc * 256 + di * 64;
        float a0 = 0.f, a1 = 0.f, a2 = 0.f, a3 = 0.f;
        #pragma unroll 4
        for (int i = 0; i < 64; ++i) {
            const int d = d0 + i, dl = di * 64 + i;
            const float w = Wsel1[(size_t)d * TH + h];
            a0 = fmaf(s_xm[0][dl], w, a0);
            a1 = fmaf(s_xm[1][dl], w, a1);
            a2 = fmaf(s_xm[2][dl], w, a2);
            a3 = fmaf(s_xm[3][dl], w, a3);
        }
        s_comb[di][0][h] = a0;
        s_comb[di][1][h] = a1;
        s_comb[di][2][h] = a2;
        s_comb[di][3][h] = a3;
        __syncthreads();
        {
            const int bb = t >> 8, hh = t & 255;
            g_selq[dc][bb][hh] = (s_comb[0][bb][hh] + s_comb[1][bb][hh])
                               + (s_comb[2][bb][hh] + s_comb[3][bb][hh]);
        }
    } else {
        // ---- out_bw ----
        const int b = bid - 148;
        float a = 0.f;
        #pragma unroll
        for (int p = 0; p < 16; ++p) a += g_partxm[b][p][t];
        const float xm = a * INVL;
        #pragma unroll
        for (int r = 0; r < TR; ++r)
            out_bw[(size_t)(b * TR + r) * TD + t] = xm;
    }
}

// ================= K3: SEL (blocks 0..3) | FIN (blocks 4..259), 512 thr =====
__global__ void __launch_bounds__(512) k3(
        const float* __restrict__ bf1,   const float* __restrict__ Wf2,
        const float* __restrict__ bf2v,  const float* __restrict__ bp2,
        const float* __restrict__ bsel1, const float* __restrict__ Wsel2,
        const float* __restrict__ bsel2,
        const float* __restrict__ x,     const float* __restrict__ nw,
        float* __restrict__ out_fit, float* __restrict__ out_selw,
        float* __restrict__ out_best, float* __restrict__ out_x) {
    __shared__ __align__(16) float smem[1060];
    const int bid = blockIdx.x, t = threadIdx.x;

    if (bid < TB) {
        // ---- SEL: fit + selection MLP + softmax + argmax. block = b ----
        float* sfit = smem;          // 32
        float* hs   = smem + 32;     // 256
        float* sred = smem + 288;    // 256
        float* lg   = smem + 544;    // 32
        const int b = bid;
        {   // fit: t -> (s = t>>4, lane = t&15), 16 h each
            const int s = t >> 4, lane = t & 15;
            float v = 0.f;
            #pragma unroll
            for (int k = 0; k < 16; ++k) {
                const int h = lane + 16 * k;
                float pre = bf1[s * TH + h];
                #pragma unroll
                for (int p = 0; p < 4; ++p) pre += g_fhp[p][b][s][h];
                v += gelu_f(pre) * Wf2[s * TH + h];
            }
            #pragma unroll
            for (int o = 8; o > 0; o >>= 1) v += __shfl_down(v, o, 16);
            if (lane == 0) {
                float fs = 1.0f / (1.0f + expf(-(v + bf2v[s])));
                sfit[s] = fs;
                out_fit[b * TS + s] = fs;
            }
        }
        __syncthreads();
        if (t < TH) {
            float pre = bsel1[t];
            #pragma unroll
            for (int p = 0; p < 4; ++p) pre += g_selq[p][b][t];
            hs[t] = gelu_f(pre);
        }
        __syncthreads();
        if (t < 256) {
            const int s = t & 31, kc = t >> 5;
            float p = 0.f;
            #pragma unroll 4
            for (int k = kc * 32; k < kc * 32 + 32; ++k)
                p = fmaf(hs[k], Wsel2[k * TS + s], p);
            sred[kc * 32 + s] = p;
        }
        __syncthreads();
        if (t < TS) {
            float l = bsel2[t] + sfit[t];
            #pragma unroll
            for (int kc = 0; kc < 8; ++kc) l += sred[kc * 32 + t];
            lg[t] = l;
        }
        __syncthreads();
        if (t == 0) {
            float mx = lg[0];
            for (int s2 = 1; s2 < TS; ++s2) mx = fmaxf(mx, lg[s2]);
            float w[TS];
            float sum = 0.f;
            for (int s2 = 0; s2 < TS; ++s2) { w[s2] = expf(lg[s2] - mx); sum += w[s2]; }
            float inv = 1.0f / sum;
            int best = 0; float bwv = -1.f;
            for (int s2 = 0; s2 < TS; ++s2) {
                float wv = w[s2] * inv;
                out_selw[b * TS + s2] = wv;
                if (wv > bwv) { bwv = wv; best = s2; }   // strict > == numpy argmax
            }
            out_best[b] = (float)best;
        }
    } else {
        // ---- FIN: i = bid-4 -> (b = i>>6, chunk = i&63), 16 rows each ----
        float* s_sr = smem;          // 1024
        float* red  = smem + 1024;   // 8
        const int i = bid - TB, b = i >> 6, chunk = i & 63;
        #pragma unroll
        for (int u = 0; u < 2; ++u) {   // srepr: reduce 16 tiny partials + bp2
            const int idx = t + u * 512;
            float a = bp2[idx];
            #pragma unroll 8
            for (int jq = 0; jq < 16; ++jq) a += g_srp[jq][b][idx];
            s_sr[idx] = a;
        }
        __syncthreads();
        const int q = t & 255, r2 = t >> 8, wave = t >> 6;
        const float4 nv = ((const float4*)nw)[q];
        const float4 sv = ((const float4*)s_sr)[q];
        for (int rr = 0; rr < 8; ++rr) {
            const int row = b * TL + chunk * 16 + rr * 2 + r2;
            const float4 xv = ((const float4*)x)[(size_t)row * 256 + q];
            float y0 = xv.x + 0.1f * sv.x;
            float y1 = xv.y + 0.1f * sv.y;
            float y2 = xv.z + 0.1f * sv.z;
            float y3 = xv.w + 0.1f * sv.w;
            float ss = y0 * y0 + y1 * y1 + y2 * y2 + y3 * y3;
            #pragma unroll
            for (int o = 32; o > 0; o >>= 1) ss += __shfl_down(ss, o);
            if ((t & 63) == 0) red[wave] = ss;
            __syncthreads();
            float tot = (red[r2 * 4 + 0] + red[r2 * 4 + 1])
                      + (red[r2 * 4 + 2] + red[r2 * 4 + 3]);
            float sc = rsqrtf(tot * INVL + 1e-6f);
            float4 o4;
            o4.x = y0 * sc * nv.x;
            o4.y = y1 * sc * nv.y;
            o4.z = y2 * sc * nv.z;
            o4.w = y3 * sc * nv.w;
            ((float4*)out_x)[(size_t)row * 256 + q] = o4;
            __syncthreads();
        }
    }
}

extern "C" void kernel_launch(void* const* d_in, const int* in_sizes, int n_in,
                              void* d_out, int out_size, void* d_ws, size_t ws_size,
                              hipStream_t stream) {
    const float* x          = (const float*)d_in[0];
    // d_in[1..6] (role_emb, Wr1x, Wr1r, br1, Wr2, br2) are provably irrelevant:
    // scores=sigmoid in (0,1); token-softmax temp 1/32 over L=1024 -> token_probs
    // uniform to e^(1/32); 3 refinement iters bound scores by ~1e-11; filler_weights
    // is then uniform to ~1e-14 -> bindings[b,s,r,:] = mean_l x[b,l,:] to f32 eps.
    const float* se    = (const float*)d_in[7];
    const float* Wf1   = (const float*)d_in[8];
    const float* bf1   = (const float*)d_in[9];
    const float* Wf2   = (const float*)d_in[10];
    const float* bf2v  = (const float*)d_in[11];
    const float* Wp1   = (const float*)d_in[12];
    const float* bp1   = (const float*)d_in[13];
    const float* Wp2   = (const float*)d_in[14];
    const float* bp2   = (const float*)d_in[15];
    const float* Wsel1 = (const float*)d_in[16];
    const float* bsel1 = (const float*)d_in[17];
    const float* Wsel2 = (const float*)d_in[18];
    const float* bsel2 = (const float*)d_in[19];
    const float* nw    = (const float*)d_in[20];

    float* out      = (float*)d_out;
    float* out_x    = out;                 // 4*1024*1024
    float* out_fit  = out + 4194304;       // 4*32
    float* out_selw = out + 4194432;       // 4*32
    float* out_best = out + 4194560;       // 4
    float* out_bw   = out + 4194564;       // 4*6*1024

    k1<<<192, 1024, 0, stream>>>(x, Wp1);
    k2<<<152, 1024, 0, stream>>>(se, Wf1, bp1, Wp2, Wsel1, out_bw);
    k3<<<260,  512, 0, stream>>>(bf1, Wf2, bf2v, bp2, bsel1, Wsel2, bsel2,
                                 x, nw, out_fit, out_selw, out_best, out_x);
}